// Round 9
// baseline (3124.321 us; speedup 1.0000x reference)
//
#include <hip/hip_runtime.h>
#include <hip/hip_bf16.h>
#include <math.h>

typedef __bf16 bf16_t;
typedef __attribute__((ext_vector_type(8))) __bf16 bf16x8;
typedef __attribute__((ext_vector_type(4))) float f32x4;

#define B_  4
#define L_  1024
#define D_  1024
#define H_  16
#define HD_ 64
#define NL_ 8
#define V_  32000
#define FF_ 4096

// ---------------- embed + sinusoidal PE -> f32 residual ----------------
__global__ __launch_bounds__(256) void embed_kernel(const int* __restrict__ idx,
                                                    const float* __restrict__ emb,
                                                    float* __restrict__ x) {
  int token = blockIdx.x;           // b*L + l
  int l = token & (L_ - 1);
  int id = idx[token];
  const float* erow = emb + (size_t)id * D_;
  float* xrow = x + (size_t)token * D_;
  int d0 = threadIdx.x * 4;
#pragma unroll
  for (int j = 0; j < 4; ++j) {
    int d = d0 + j;
    int i = d >> 1;
    float freq = expf((float)(2 * i) * (-9.210340371976184f / (float)D_));
    float ang = (float)l * freq;
    float pe = (d & 1) ? cosf(ang) : sinf(ang);
    xrow[d] = erow[d] + pe;
  }
}

// ---------------- LayerNorm: f32 in -> bf16 out ----------------
__global__ __launch_bounds__(256) void ln_kernel(const float* __restrict__ x,
                                                 const float* __restrict__ gamma,
                                                 const float* __restrict__ beta,
                                                 bf16_t* __restrict__ out) {
  int row = blockIdx.x;
  int t = threadIdx.x;
  float4 v = ((const float4*)(x + (size_t)row * D_))[t];
  float va[4] = {v.x, v.y, v.z, v.w};
  float s = va[0] + va[1] + va[2] + va[3];
  float ss = va[0]*va[0] + va[1]*va[1] + va[2]*va[2] + va[3]*va[3];
#pragma unroll
  for (int m = 1; m < 64; m <<= 1) {
    s  += __shfl_xor(s, m);
    ss += __shfl_xor(ss, m);
  }
  __shared__ float red[8];
  int wid = t >> 6, lane = t & 63;
  if (lane == 0) { red[wid] = s; red[4 + wid] = ss; }
  __syncthreads();
  s  = red[0] + red[1] + red[2] + red[3];
  ss = red[4] + red[5] + red[6] + red[7];
  float mu  = s * (1.0f / D_);
  float var = fmaxf(ss * (1.0f / D_) - mu * mu, 0.0f);
  float rstd = rsqrtf(var + 1e-5f);
  int d0 = t * 4;
  bf16_t* orow = out + (size_t)row * D_ + d0;
#pragma unroll
  for (int j = 0; j < 4; ++j) {
    int d = d0 + j;
    orow[j] = (bf16_t)((va[j] - mu) * rstd * gamma[d] + beta[d]);
  }
}

// ------- transpose + f32->bf16: in[base + k*ldin + n] -> out[n*K + k], n<N,k<K -------
__global__ void transpose_k(const float* __restrict__ in, size_t base,
                            bf16_t* __restrict__ out, int K, int N, int ldin) {
  __shared__ bf16_t tile[32][33];
  int n0 = blockIdx.x * 32, k0 = blockIdx.y * 32;
#pragma unroll
  for (int r = 0; r < 4; ++r) {
    int kk = threadIdx.y + r * 8;
    tile[kk][threadIdx.x] = (bf16_t)in[base + (size_t)(k0 + kk) * ldin + n0 + threadIdx.x];
  }
  __syncthreads();
#pragma unroll
  for (int r = 0; r < 4; ++r) {
    int nn = threadIdx.y + r * 8;
    out[(size_t)(n0 + nn) * K + k0 + threadIdx.x] = tile[threadIdx.x][nn];
  }
}

// ------- fused QKV transpose: z selects wq/wk/wv; out row offset z*D -------
__global__ void transpose_qkv(const float* __restrict__ wq,
                              const float* __restrict__ wk,
                              const float* __restrict__ wv, size_t base,
                              bf16_t* __restrict__ out) {
  const float* in = (blockIdx.z == 0) ? wq : (blockIdx.z == 1) ? wk : wv;
  __shared__ bf16_t tile[32][33];
  int n0 = blockIdx.x * 32, k0 = blockIdx.y * 32;
#pragma unroll
  for (int r = 0; r < 4; ++r) {
    int kk = threadIdx.y + r * 8;
    tile[kk][threadIdx.x] = (bf16_t)in[base + (size_t)(k0 + kk) * D_ + n0 + threadIdx.x];
  }
  __syncthreads();
  bf16_t* o = out + (size_t)blockIdx.z * D_ * D_;
#pragma unroll
  for (int r = 0; r < 4; ++r) {
    int nn = threadIdx.y + r * 8;
    o[(size_t)(n0 + nn) * D_ + k0 + threadIdx.x] = tile[threadIdx.x][nn];
  }
}

// ---------------- async global->LDS helper ----------------
__device__ __forceinline__ void gload_lds16(const bf16_t* g, bf16_t* lds) {
  __builtin_amdgcn_global_load_lds(
      (const __attribute__((address_space(1))) void*)g,
      (__attribute__((address_space(3))) void*)(void*)lds,
      16, 0, 0);
}

// ---- common bijective XCD + grouped-raster block remap (G=8 bm rows/group) ----
__device__ __forceinline__ void remap_block(int& bn, int& bm) {
  const int gx = gridDim.x, gy = gridDim.y;
  int lin = blockIdx.y * gx + blockIdx.x;
  int nwg = gx * gy;
  int q8 = nwg >> 3, r8 = nwg & 7;
  int xcd = lin & 7, pos = lin >> 3;
  int wg = (xcd < r8 ? xcd * (q8 + 1) : r8 * (q8 + 1) + (xcd - r8) * q8) + pos;
  if ((gy & 7) == 0) {
    int per = gx << 3;
    int grp = wg / per, win = wg % per;
    bm = (grp << 3) + (win & 7);
    bn = win >> 3;
  } else { bn = wg % gx; bm = wg / gx; }
}

// ---------------- 128x128 GEMM (m97 structure), kept for N=1024 shapes ----------------
// EPI: 1 = resid f32 +=; 3 = resid += (+bias)
template <int EPI>
__global__ __launch_bounds__(256) void gemm_bt_kernel(
    const bf16_t* __restrict__ A, const bf16_t* __restrict__ Bt,
    bf16_t* __restrict__ outb, float* __restrict__ outf,
    const float* __restrict__ bias, int M, int Nst, int K, int col0) {
  int bn, bm; remap_block(bn, bm);
  const int tid = threadIdx.x, wid = tid >> 6, lane = tid & 63;
  const int wm = wid >> 1, wn = wid & 1;
  const int l15 = lane & 15, l4 = lane >> 4;

  __shared__ __align__(16) bf16_t As[128 * 32];
  __shared__ __align__(16) bf16_t Bs[128 * 32];

  f32x4 acc[4][4] = {};

  const bf16_t* Ablk = A  + (size_t)(bm * 128) * K;
  const bf16_t* Bblk = Bt + (size_t)(bn * 128) * K;
  const int srow = lane >> 2;
  const int skof = (lane & 3) * 8;

  for (int k0 = 0; k0 < K; k0 += 32) {
#pragma unroll
    for (int c = 0; c < 2; ++c) {
      int chunk = wid * 2 + c;
      int row = chunk * 16 + srow;
      gload_lds16(Ablk + (size_t)row * K + k0 + skof, As + chunk * 512);
      gload_lds16(Bblk + (size_t)row * K + k0 + skof, Bs + chunk * 512);
    }
    __syncthreads();

    bf16x8 af[4], bfv[4];
#pragma unroll
    for (int i = 0; i < 4; ++i)
      af[i] = *(const bf16x8*)(As + (wm * 64 + i * 16 + l15) * 32 + l4 * 8);
#pragma unroll
    for (int j = 0; j < 4; ++j)
      bfv[j] = *(const bf16x8*)(Bs + (wn * 64 + j * 16 + l15) * 32 + l4 * 8);
#pragma unroll
    for (int i = 0; i < 4; ++i)
#pragma unroll
      for (int j = 0; j < 4; ++j)
        acc[i][j] = __builtin_amdgcn_mfma_f32_16x16x32_bf16(af[i], bfv[j], acc[i][j], 0, 0, 0);
    __syncthreads();
  }

  const int row_base = bm * 128 + wm * 64;
  const int col_base = col0 + bn * 128 + wn * 64 + l15;
#pragma unroll
  for (int i = 0; i < 4; ++i) {
#pragma unroll
    for (int j = 0; j < 4; ++j) {
      int col = col_base + j * 16;
#pragma unroll
      for (int r = 0; r < 4; ++r) {
        int row = row_base + i * 16 + l4 * 4 + r;
        float val = acc[i][j][r];
        if (EPI == 1) {
          outf[(size_t)row * Nst + col] += val;
        } else {
          outf[(size_t)row * Nst + col] += val + bias[col];
        }
      }
    }
  }
}

// ---------------- 256x256 8-wave GEMM, BK=32, 64 KiB LDS -> 2 blocks/CU ----------------
// Double-buffered; ONE vmcnt(0)+barrier per K-tile (drain covered by co-resident block).
// T2 swizzle at 4 slots/row: LDS[row][s] holds global slot s ^ (row&3).
// EPI: 2 = +bias, gelu, store bf16; 4 = store f32; 5 = QKV split store
template <int EPI>
__global__ __launch_bounds__(512, 2) void gemm256_kernel(
    const bf16_t* __restrict__ A, const bf16_t* __restrict__ Bt,
    bf16_t* __restrict__ outb, float* __restrict__ outf,
    const float* __restrict__ bias, int M, int Nst, int K, int col0) {
  int bn, bm; remap_block(bn, bm);
  const int tid = threadIdx.x, wid = tid >> 6, lane = tid & 63;
  const int wm = wid >> 2, wn = wid & 3;          // 2 x 4 waves
  const int l15 = lane & 15, l4 = lane >> 4;

  // [2 bufs][ A 256x32 | B 256x32 ] bf16 = 64 KiB
  __shared__ __align__(16) bf16_t smem[32768];

  f32x4 acc[8][4] = {};

  const bf16_t* Ab = A  + (size_t)(bm * 256) * K;
  const bf16_t* Bb = Bt + (size_t)(bn * 256) * K;
  const int NT = K >> 5;

  const int srow16 = lane >> 2;                    // 0..15 within 16-row chunk
  const int sslot  = lane & 3;
  const int xrd    = l15 & 3;                      // read-side row&3

  auto stage = [&](int t, int pbuf) {
    bf16_t* base = smem + pbuf * 16384;
#pragma unroll
    for (int c = 0; c < 2; ++c) {
      int row = c * 128 + wid * 16 + srow16;
      int gs  = sslot ^ (row & 3);
      const size_t go = (size_t)row * K + t * 32 + gs * 8;
      gload_lds16(Bb + go, base + 8192 + c * 4096 + wid * 512);
      gload_lds16(Ab + go, base +        c * 4096 + wid * 512);
    }
  };

  stage(0, 0);
  asm volatile("s_waitcnt vmcnt(0)" ::: "memory");
  __builtin_amdgcn_s_barrier();

  for (int t = 0; t < NT; ++t) {
    const int pb = t & 1;
    const bf16_t* sA = smem + pb * 16384;
    const bf16_t* sB = sA + 8192;
    const bool pre = (t + 1 < NT);
    if (pre) stage(t + 1, pb ^ 1);   // 4 loads/wave; in flight across this tile

    bf16x8 bfr[4];
#pragma unroll
    for (int n = 0; n < 4; ++n)
      bfr[n] = *(const bf16x8*)(sB + (wn * 64 + n * 16 + l15) * 32 + ((l4 ^ xrd) & 3) * 8);

    __builtin_amdgcn_s_setprio(1);
#pragma unroll
    for (int m = 0; m < 8; ++m) {
      bf16x8 af = *(const bf16x8*)(sA + (wm * 128 + m * 16 + l15) * 32 + ((l4 ^ xrd) & 3) * 8);
#pragma unroll
      for (int n = 0; n < 4; ++n)
        acc[m][n] = __builtin_amdgcn_mfma_f32_16x16x32_bf16(af, bfr[n], acc[m][n], 0, 0, 0);
    }
    __builtin_amdgcn_s_setprio(0);

    if (pre) { asm volatile("s_waitcnt vmcnt(0)" ::: "memory"); }
    __builtin_amdgcn_s_barrier();    // next tile resident; this tile's reads done
  }

  // epilogue: row = bm*256 + wm*128 + m*16 + l4*4 + r ; col = col0 + bn*256 + wn*64 + n*16 + l15
  const int row_base = bm * 256 + wm * 128;
#pragma unroll
  for (int m = 0; m < 8; ++m) {
#pragma unroll
    for (int n = 0; n < 4; ++n) {
      int colg = bn * 256 + wn * 64 + n * 16 + l15;
#pragma unroll
      for (int r = 0; r < 4; ++r) {
        int row = row_base + m * 16 + l4 * 4 + r;
        float val = acc[m][n][r];
        if (EPI == 4) {
          outf[(size_t)row * Nst + col0 + colg] = val;
        } else if (EPI == 2) {
          int col = col0 + colg;
          float v2 = val + bias[col];
          v2 = 0.5f * v2 * (1.0f + erff(v2 * 0.7071067811865475f));
          outb[(size_t)row * Nst + col] = (bf16_t)v2;
        } else {   // EPI 5: QKV split into three contiguous [M,1024] buffers
          int buf = colg >> 10;
          int lc  = colg & 1023;
          (outb + (size_t)buf * 4194304)[(size_t)row * 1024 + lc] = (bf16_t)val;
        }
      }
    }
  }
}

// ---------------- flash attention (causal), 1 block = (b, h, 64 q-rows) ----------------
// V stored column-rotated: Vs[d][ (j + (d&56)) & 63 ] = V[j][d]  -> conflict-free
__global__ __launch_bounds__(256) void attn_kernel(
    const bf16_t* __restrict__ q, const bf16_t* __restrict__ k,
    const bf16_t* __restrict__ v, bf16_t* __restrict__ y) {
  int bid = blockIdx.x;
  int qt = bid & 15;
  int h  = (bid >> 4) & (H_ - 1);
  int b  = bid >> 8;
  int tid = threadIdx.x, wid = tid >> 6, lane = tid & 63;
  int l15 = lane & 15, l4 = lane >> 4;

  __shared__ __align__(16) bf16_t Ks[64 * 72];
  __shared__ __align__(16) bf16_t Vs[64 * 72];
  __shared__ __align__(16) bf16_t Ps[4][16 * 72];

  const int qrow0 = qt * 64 + wid * 16;
  const size_t bh = ((size_t)b * L_ * H_ + h) * HD_;

  bf16x8 qf[2];
#pragma unroll
  for (int c = 0; c < 2; ++c)
    qf[c] = *(const bf16x8*)(q + bh + (size_t)(qrow0 + l15) * (H_ * HD_) + c * 32 + l4 * 8);

  float m_r[4] = {-INFINITY, -INFINITY, -INFINITY, -INFINITY};
  float l_r[4] = {0.f, 0.f, 0.f, 0.f};
  f32x4 oacc[4] = {};

  for (int kt = 0; kt <= qt; ++kt) {
    __syncthreads();
    int kbase = kt * 64;
#pragma unroll
    for (int s = 0; s < 2; ++s) {
      int seg = s * 256 + tid;
      int j = seg >> 3;
      int dof = (seg & 7) * 8;
      const size_t src = bh + (size_t)(kbase + j) * (H_ * HD_) + dof;
      *(bf16x8*)(Ks + j * 72 + dof) = *(const bf16x8*)(k + src);
      bf16x8 vv = *(const bf16x8*)(v + src);
      int colb = (j + dof) & 63;
#pragma unroll
      for (int jj = 0; jj < 8; ++jj) Vs[(dof + jj) * 72 + colb] = vv[jj];
    }
    __syncthreads();

    f32x4 sacc[4] = {};
#pragma unroll
    for (int c = 0; c < 2; ++c) {
#pragma unroll
      for (int t = 0; t < 4; ++t) {
        bf16x8 kf = *(const bf16x8*)(Ks + (t * 16 + l15) * 72 + c * 32 + l4 * 8);
        sacc[t] = __builtin_amdgcn_mfma_f32_16x16x32_bf16(qf[c], kf, sacc[t], 0, 0, 0);
      }
    }

    float tmax[4] = {-INFINITY, -INFINITY, -INFINITY, -INFINITY};
#pragma unroll
    for (int t = 0; t < 4; ++t) {
#pragma unroll
      for (int r = 0; r < 4; ++r) {
        float sv = sacc[t][r] * 0.125f;
        int kj = kbase + t * 16 + l15;
        int qi = qrow0 + l4 * 4 + r;
        if (kj > qi) sv = -INFINITY;
        sacc[t][r] = sv;
        tmax[r] = fmaxf(tmax[r], sv);
      }
    }
#pragma unroll
    for (int r = 0; r < 4; ++r) {
#pragma unroll
      for (int md = 1; md < 16; md <<= 1)
        tmax[r] = fmaxf(tmax[r], __shfl_xor(tmax[r], md));
    }
    float alpha[4], tsum[4];
#pragma unroll
    for (int r = 0; r < 4; ++r) {
      float mn = fmaxf(m_r[r], tmax[r]);
      alpha[r] = expf(m_r[r] - mn);
      m_r[r] = mn;
      tsum[r] = 0.f;
    }
#pragma unroll
    for (int t = 0; t < 4; ++t) {
#pragma unroll
      for (int r = 0; r < 4; ++r) {
        float p = expf(sacc[t][r] - m_r[r]);
        tsum[r] += p;
        Ps[wid][(l4 * 4 + r) * 72 + t * 16 + l15] = (bf16_t)p;
      }
    }
#pragma unroll
    for (int r = 0; r < 4; ++r) {
#pragma unroll
      for (int md = 1; md < 16; md <<= 1)
        tsum[r] += __shfl_xor(tsum[r], md);
      l_r[r] = l_r[r] * alpha[r] + tsum[r];
    }
#pragma unroll
    for (int t = 0; t < 4; ++t)
#pragma unroll
      for (int r = 0; r < 4; ++r)
        oacc[t][r] *= alpha[r];

#pragma unroll
    for (int c = 0; c < 2; ++c) {
      bf16x8 pf = *(const bf16x8*)(&Ps[wid][l15 * 72 + c * 32 + l4 * 8]);
#pragma unroll
      for (int t = 0; t < 4; ++t) {
        int d = t * 16 + l15;
        int jb = c * 32 + l4 * 8;
        bf16x8 vf = *(const bf16x8*)(Vs + d * 72 + ((jb + (d & 56)) & 63));
        oacc[t] = __builtin_amdgcn_mfma_f32_16x16x32_bf16(pf, vf, oacc[t], 0, 0, 0);
      }
    }
  }

#pragma unroll
  for (int t = 0; t < 4; ++t) {
#pragma unroll
    for (int r = 0; r < 4; ++r) {
      int row = qrow0 + l4 * 4 + r;
      int d = t * 16 + l15;
      y[bh + (size_t)row * (H_ * HD_) + d] = (bf16_t)(oacc[t][r] / l_r[r]);
    }
  }
}

// ---------------- host launcher ----------------
extern "C" void kernel_launch(void* const* d_in, const int* in_sizes, int n_in,
                              void* d_out, int out_size, void* d_ws, size_t ws_size,
                              hipStream_t stream) {
  (void)in_sizes; (void)n_in; (void)out_size;
  const int*   idx   = (const int*)d_in[0];
  const float* emb   = (const float*)d_in[1];
  const float* ln1_s = (const float*)d_in[2];
  const float* ln1_b = (const float*)d_in[3];
  const float* wq    = (const float*)d_in[4];
  const float* wk    = (const float*)d_in[5];
  const float* wv    = (const float*)d_in[6];
  const float* wo    = (const float*)d_in[7];
  const float* ln2_s = (const float*)d_in[8];
  const float* ln2_b = (const float*)d_in[9];
  const float* w1    = (const float*)d_in[10];
  const float* b1    = (const float*)d_in[11];
  const float* w2    = (const float*)d_in[12];
  const float* b2    = (const float*)d_in[13];
  const float* lnf_s = (const float*)d_in[14];
  const float* lnf_b = (const float*)d_in[15];
  const float* headw = (const float*)d_in[16];
  float* out = (float*)d_out;

  char* ws = (char*)d_ws;
  const size_t XO  = 0;
  const size_t HBO = XO  + 16777216;     // f32 residual 4096x1024
  const size_t QBO = HBO + 8388608;      // bf16 4096x1024 each; Q,K,V contiguous
  const size_t KBO = QBO + 8388608;
  const size_t VBO = KBO + 8388608;
  const size_t YBO = VBO + 8388608;
  const size_t GBO = QBO;                // FFN intermediate overlaps Q/K/V/Y
  const size_t WTO = YBO + 8388608;      // transposed-weight staging

  float*  X  = (float*)(ws + XO);
  bf16_t* Hb = (bf16_t*)(ws + HBO);
  bf16_t* Qb = (bf16_t*)(ws + QBO);
  bf16_t* Kb = (bf16_t*)(ws + KBO);
  bf16_t* Vb = (bf16_t*)(ws + VBO);
  bf16_t* Yb = (bf16_t*)(ws + YBO);
  bf16_t* Gb = (bf16_t*)(ws + GBO);
  bf16_t* WT = (bf16_t*)(ws + WTO);

  const int M = B_ * L_;                 // 4096
  const dim3 tb(32, 8);

  embed_kernel<<<M, 256, 0, stream>>>(idx, emb, X);

  for (int l = 0; l < NL_; ++l) {
    const size_t wof = (size_t)l * D_ * D_;
    ln_kernel<<<M, 256, 0, stream>>>(X, ln1_s + (size_t)l * D_, ln1_b + (size_t)l * D_, Hb);

    // fused QKV: WT rows [0,1024)=wq^T, [1024,2048)=wk^T, [2048,3072)=wv^T
    transpose_qkv<<<dim3(D_/32, D_/32, 3), tb, 0, stream>>>(wq, wk, wv, wof, WT);
    gemm256_kernel<5><<<dim3(3*D_/256, M/256), 512, 0, stream>>>(Hb, WT, Qb, nullptr, nullptr, M, D_, D_, 0);

    attn_kernel<<<B_ * H_ * (L_/64), 256, 0, stream>>>(Qb, Kb, Vb, Yb);

    transpose_k<<<dim3(D_/32, D_/32), tb, 0, stream>>>(wo, wof, WT, D_, D_, D_);
    gemm_bt_kernel<1><<<dim3(D_/128, M/128), 256, 0, stream>>>(Yb, WT, nullptr, X, nullptr, M, D_, D_, 0);

    ln_kernel<<<M, 256, 0, stream>>>(X, ln2_s + (size_t)l * D_, ln2_b + (size_t)l * D_, Hb);

    transpose_k<<<dim3(FF_/32, D_/32), tb, 0, stream>>>(w1, (size_t)l * D_ * FF_, WT, D_, FF_, FF_);
    gemm256_kernel<2><<<dim3(FF_/256, M/256), 512, 0, stream>>>(Hb, WT, Gb, nullptr, b1 + (size_t)l * FF_, M, FF_, D_, 0);

    transpose_k<<<dim3(D_/32, FF_/32), tb, 0, stream>>>(w2, (size_t)l * FF_ * D_, WT, FF_, D_, D_);
    gemm_bt_kernel<3><<<dim3(D_/128, M/128), 256, 0, stream>>>(Gb, WT, nullptr, X, b2 + (size_t)l * D_, M, D_, FF_, 0);
  }

  ln_kernel<<<M, 256, 0, stream>>>(X, lnf_s, lnf_b, Hb);

  // head GEMM -> f32 logits, N-chunked (256-multiples) to fit ws
  size_t avail = (ws_size > WTO) ? (ws_size - WTO) : 0;
  long long maxcols = (long long)(avail / ((size_t)D_ * 2));
  int chunk = (int)((maxcols / 256) * 256);
  if (chunk > V_) chunk = V_;
  if (chunk < 256) chunk = 256;
  for (int n0 = 0; n0 < V_; n0 += chunk) {
    int nc = (V_ - n0 < chunk) ? (V_ - n0) : chunk;
    transpose_k<<<dim3(nc/32, D_/32), tb, 0, stream>>>(headw, (size_t)n0, WT, D_, nc, V_);
    gemm256_kernel<4><<<dim3(nc/256, M/256), 512, 0, stream>>>(Hb, WT, nullptr, out, nullptr, M, V_, D_, n0);
  }
}

// Round 11
// 3037.288 us; speedup vs baseline: 1.0287x; 1.0287x over previous
//
#include <hip/hip_runtime.h>
#include <hip/hip_bf16.h>
#include <math.h>

typedef __bf16 bf16_t;
typedef __attribute__((ext_vector_type(8))) __bf16 bf16x8;
typedef __attribute__((ext_vector_type(4))) float f32x4;

#define B_  4
#define L_  1024
#define D_  1024
#define H_  16
#define HD_ 64
#define NL_ 8
#define V_  32000
#define FF_ 4096

// ---------------- embed + sinusoidal PE -> f32 residual ----------------
__global__ __launch_bounds__(256) void embed_kernel(const int* __restrict__ idx,
                                                    const float* __restrict__ emb,
                                                    float* __restrict__ x) {
  int token = blockIdx.x;           // b*L + l
  int l = token & (L_ - 1);
  int id = idx[token];
  const float* erow = emb + (size_t)id * D_;
  float* xrow = x + (size_t)token * D_;
  int d0 = threadIdx.x * 4;
#pragma unroll
  for (int j = 0; j < 4; ++j) {
    int d = d0 + j;
    int i = d >> 1;
    float freq = expf((float)(2 * i) * (-9.210340371976184f / (float)D_));
    float ang = (float)l * freq;
    float pe = (d & 1) ? cosf(ang) : sinf(ang);
    xrow[d] = erow[d] + pe;
  }
}

// ---------------- LayerNorm: f32 in -> bf16 out ----------------
__global__ __launch_bounds__(256) void ln_kernel(const float* __restrict__ x,
                                                 const float* __restrict__ gamma,
                                                 const float* __restrict__ beta,
                                                 bf16_t* __restrict__ out) {
  int row = blockIdx.x;
  int t = threadIdx.x;
  float4 v = ((const float4*)(x + (size_t)row * D_))[t];
  float va[4] = {v.x, v.y, v.z, v.w};
  float s = va[0] + va[1] + va[2] + va[3];
  float ss = va[0]*va[0] + va[1]*va[1] + va[2]*va[2] + va[3]*va[3];
#pragma unroll
  for (int m = 1; m < 64; m <<= 1) {
    s  += __shfl_xor(s, m);
    ss += __shfl_xor(ss, m);
  }
  __shared__ float red[8];
  int wid = t >> 6, lane = t & 63;
  if (lane == 0) { red[wid] = s; red[4 + wid] = ss; }
  __syncthreads();
  s  = red[0] + red[1] + red[2] + red[3];
  ss = red[4] + red[5] + red[6] + red[7];
  float mu  = s * (1.0f / D_);
  float var = fmaxf(ss * (1.0f / D_) - mu * mu, 0.0f);
  float rstd = rsqrtf(var + 1e-5f);
  int d0 = t * 4;
  bf16_t* orow = out + (size_t)row * D_ + d0;
#pragma unroll
  for (int j = 0; j < 4; ++j) {
    int d = d0 + j;
    orow[j] = (bf16_t)((va[j] - mu) * rstd * gamma[d] + beta[d]);
  }
}

// ------- transpose + f32->bf16: in[base + k*ldin + n] -> out[n*K + k], n<N,k<K -------
__global__ void transpose_k(const float* __restrict__ in, size_t base,
                            bf16_t* __restrict__ out, int K, int N, int ldin) {
  __shared__ bf16_t tile[32][33];
  int n0 = blockIdx.x * 32, k0 = blockIdx.y * 32;
#pragma unroll
  for (int r = 0; r < 4; ++r) {
    int kk = threadIdx.y + r * 8;
    tile[kk][threadIdx.x] = (bf16_t)in[base + (size_t)(k0 + kk) * ldin + n0 + threadIdx.x];
  }
  __syncthreads();
#pragma unroll
  for (int r = 0; r < 4; ++r) {
    int nn = threadIdx.y + r * 8;
    out[(size_t)(n0 + nn) * K + k0 + threadIdx.x] = tile[threadIdx.x][nn];
  }
}

// ------- fused QKV transpose: z selects wq/wk/wv; out row offset z*D -------
__global__ void transpose_qkv(const float* __restrict__ wq,
                              const float* __restrict__ wk,
                              const float* __restrict__ wv, size_t base,
                              bf16_t* __restrict__ out) {
  const float* in = (blockIdx.z == 0) ? wq : (blockIdx.z == 1) ? wk : wv;
  __shared__ bf16_t tile[32][33];
  int n0 = blockIdx.x * 32, k0 = blockIdx.y * 32;
#pragma unroll
  for (int r = 0; r < 4; ++r) {
    int kk = threadIdx.y + r * 8;
    tile[kk][threadIdx.x] = (bf16_t)in[base + (size_t)(k0 + kk) * D_ + n0 + threadIdx.x];
  }
  __syncthreads();
  bf16_t* o = out + (size_t)blockIdx.z * D_ * D_;
#pragma unroll
  for (int r = 0; r < 4; ++r) {
    int nn = threadIdx.y + r * 8;
    o[(size_t)(n0 + nn) * D_ + k0 + threadIdx.x] = tile[threadIdx.x][nn];
  }
}

// ---------------- async global->LDS helper ----------------
__device__ __forceinline__ void gload_lds16(const bf16_t* g, bf16_t* lds) {
  __builtin_amdgcn_global_load_lds(
      (const __attribute__((address_space(1))) void*)g,
      (__attribute__((address_space(3))) void*)(void*)lds,
      16, 0, 0);
}

// ---- common bijective XCD + grouped-raster block remap (G=8 bm rows/group) ----
__device__ __forceinline__ void remap_block(int& bn, int& bm) {
  const int gx = gridDim.x, gy = gridDim.y;
  int lin = blockIdx.y * gx + blockIdx.x;
  int nwg = gx * gy;
  int q8 = nwg >> 3, r8 = nwg & 7;
  int xcd = lin & 7, pos = lin >> 3;
  int wg = (xcd < r8 ? xcd * (q8 + 1) : r8 * (q8 + 1) + (xcd - r8) * q8) + pos;
  if ((gy & 7) == 0) {
    int per = gx << 3;
    int grp = wg / per, win = wg % per;
    bm = (grp << 3) + (win & 7);
    bn = win >> 3;
  } else { bn = wg % gx; bm = wg / gx; }
}

// ---------------- 128x128 GEMM (m97 structure), kept for N=1024 shapes ----------------
// EPI: 1 = resid f32 +=; 3 = resid += (+bias)
template <int EPI>
__global__ __launch_bounds__(256) void gemm_bt_kernel(
    const bf16_t* __restrict__ A, const bf16_t* __restrict__ Bt,
    bf16_t* __restrict__ outb, float* __restrict__ outf,
    const float* __restrict__ bias, int M, int Nst, int K, int col0) {
  int bn, bm; remap_block(bn, bm);
  const int tid = threadIdx.x, wid = tid >> 6, lane = tid & 63;
  const int wm = wid >> 1, wn = wid & 1;
  const int l15 = lane & 15, l4 = lane >> 4;

  __shared__ __align__(16) bf16_t As[128 * 32];
  __shared__ __align__(16) bf16_t Bs[128 * 32];

  f32x4 acc[4][4] = {};

  const bf16_t* Ablk = A  + (size_t)(bm * 128) * K;
  const bf16_t* Bblk = Bt + (size_t)(bn * 128) * K;
  const int srow = lane >> 2;
  const int skof = (lane & 3) * 8;

  for (int k0 = 0; k0 < K; k0 += 32) {
#pragma unroll
    for (int c = 0; c < 2; ++c) {
      int chunk = wid * 2 + c;
      int row = chunk * 16 + srow;
      gload_lds16(Ablk + (size_t)row * K + k0 + skof, As + chunk * 512);
      gload_lds16(Bblk + (size_t)row * K + k0 + skof, Bs + chunk * 512);
    }
    __syncthreads();

    bf16x8 af[4], bfv[4];
#pragma unroll
    for (int i = 0; i < 4; ++i)
      af[i] = *(const bf16x8*)(As + (wm * 64 + i * 16 + l15) * 32 + l4 * 8);
#pragma unroll
    for (int j = 0; j < 4; ++j)
      bfv[j] = *(const bf16x8*)(Bs + (wn * 64 + j * 16 + l15) * 32 + l4 * 8);
#pragma unroll
    for (int i = 0; i < 4; ++i)
#pragma unroll
      for (int j = 0; j < 4; ++j)
        acc[i][j] = __builtin_amdgcn_mfma_f32_16x16x32_bf16(af[i], bfv[j], acc[i][j], 0, 0, 0);
    __syncthreads();
  }

  const int row_base = bm * 128 + wm * 64;
  const int col_base = col0 + bn * 128 + wn * 64 + l15;
#pragma unroll
  for (int i = 0; i < 4; ++i) {
#pragma unroll
    for (int j = 0; j < 4; ++j) {
      int col = col_base + j * 16;
#pragma unroll
      for (int r = 0; r < 4; ++r) {
        int row = row_base + i * 16 + l4 * 4 + r;
        float val = acc[i][j][r];
        if (EPI == 1) {
          outf[(size_t)row * Nst + col] += val;
        } else {
          outf[(size_t)row * Nst + col] += val + bias[col];
        }
      }
    }
  }
}

// ------- 256x256 8-wave GEMM, BK=64, 8-phase schedule, race-free stage map -------
// A read pattern: SP0 = rows {0-63,128-191} ds_read at ph1/ph5; SP1 = {64-127,192-255}
// at ph3/ph7. B halves fully retired after ph2/ph6. Stage each region ONLY after its
// last read (>=1 barrier separation):
//   ph1: B_H1(T1) | ph2: A_SP0(T0+2) | ph3: B_H0(T0+2) | ph4: A_SP1(T0+2), vmcnt(6)
//   ph5: B_H1(T0+2) | ph6: A_SP0(T1+2) | ph7: B_H0(T1+2) | ph8: A_SP1(T1+2), vmcnt(6)
// FIFO ledger: 6 outstanding entering each iter; ph4 wait drains T1's remainder,
// ph8 wait drains all of T0+2. EPI: 2 = +bias,gelu,bf16; 4 = f32; 5 = QKV split
template <int EPI>
__global__ __launch_bounds__(512, 2) void gemm256_kernel(
    const bf16_t* __restrict__ A, const bf16_t* __restrict__ Bt,
    bf16_t* __restrict__ outb, float* __restrict__ outf,
    const float* __restrict__ bias, int M, int Nst, int K, int col0) {
  int bn, bm; remap_block(bn, bm);
  const int tid = threadIdx.x, wid = tid >> 6, lane = tid & 63;
  const int wm = wid >> 2, wn = wid & 3;          // 2 x 4 waves
  const int l15 = lane & 15, l4 = lane >> 4;

  // [2 bufs][ A 256x64 | B 256x64 ] bf16 = 128 KiB
  __shared__ __align__(16) bf16_t smem[65536];

  f32x4 acc[8][4] = {};

  const bf16_t* Ab = A  + (size_t)(bm * 256) * K;
  const bf16_t* Bb = Bt + (size_t)(bn * 256) * K;
  const int NT = K >> 6;                           // even

  const int srow = tid >> 3;                       // 0..63
  const int sx8  = tid & 7;
  const int xrd  = l15 & 7;                        // read-side row&7

  // one gload: 64 rows starting at row R of tile t (mat 0=A,1=B)
  auto stage_rows = [&](int t, int mat, int R) {
    const bf16_t* g = mat ? Bb : Ab;
    bf16_t* l = smem + (t & 1) * 32768 + mat * 16384 + R * 64;
    int row = R + srow;
    int gs  = sx8 ^ (row & 7);
    gload_lds16(g + (size_t)row * K + t * 64 + gs * 8, l + wid * 512);
  };
  auto stA_SP0 = [&](int t) { stage_rows(t, 0, 0);   stage_rows(t, 0, 128); };
  auto stA_SP1 = [&](int t) { stage_rows(t, 0, 64);  stage_rows(t, 0, 192); };
  auto stB_H0  = [&](int t) { stage_rows(t, 1, 0);   stage_rows(t, 1, 64);  };
  auto stB_H1  = [&](int t) { stage_rows(t, 1, 128); stage_rows(t, 1, 192); };

  // prologue: tile0 full; tile1 A_SP0,B_H0,A_SP1 (B_H1 staged at first ph1)
  stA_SP0(0); stB_H0(0); stA_SP1(0); stB_H1(0);
  stA_SP0(1); stB_H0(1); stA_SP1(1);
  asm volatile("s_waitcnt vmcnt(6)" ::: "memory");   // tile0 resident
  __builtin_amdgcn_s_barrier();

  bf16x8 af[4][2], bfr[4][2];

  auto rdB = [&](const bf16_t* sB, int nh) {
#pragma unroll
    for (int n = 0; n < 2; ++n)
#pragma unroll
      for (int ks = 0; ks < 2; ++ks)
        bfr[nh * 2 + n][ks] = *(const bf16x8*)(sB + (wn * 64 + (nh * 2 + n) * 16 + l15) * 64
                                                  + ((ks * 4 + l4) ^ xrd) * 8);
  };
  auto rdA = [&](const bf16_t* sA, int mh) {
#pragma unroll
    for (int m = 0; m < 4; ++m)
#pragma unroll
      for (int ks = 0; ks < 2; ++ks)
        af[m][ks] = *(const bf16x8*)(sA + (wm * 128 + mh * 64 + m * 16 + l15) * 64
                                        + ((ks * 4 + l4) ^ xrd) * 8);
  };
  auto mma = [&](int mh, int nh) {
    asm volatile("s_waitcnt lgkmcnt(0)" ::: "memory");
    __builtin_amdgcn_sched_barrier(0);
    __builtin_amdgcn_s_setprio(1);
#pragma unroll
    for (int m = 0; m < 4; ++m)
#pragma unroll
      for (int n = 0; n < 2; ++n)
#pragma unroll
        for (int ks = 0; ks < 2; ++ks)
          acc[mh * 4 + m][nh * 2 + n] = __builtin_amdgcn_mfma_f32_16x16x32_bf16(
              af[m][ks], bfr[nh * 2 + n][ks], acc[mh * 4 + m][nh * 2 + n], 0, 0, 0);
    __builtin_amdgcn_s_setprio(0);
  };

  const int NI = NT >> 1;
  for (int it = 0; it < NI; ++it) {
    const int T0 = 2 * it, T1 = 2 * it + 1;
    const bool pre = (it + 1 < NI);
    const bf16_t* sA0 = smem;            // buf0: even tile
    const bf16_t* sB0 = smem + 16384;
    const bf16_t* sA1 = smem + 32768;    // buf1: odd tile
    const bf16_t* sB1 = smem + 49152;

    // ph1
    rdB(sB0, 0); rdA(sA0, 0);
    stB_H1(T1);
    __builtin_amdgcn_s_barrier();
    mma(0, 0);
    __builtin_amdgcn_s_barrier();
    // ph2
    rdB(sB0, 1);
    if (pre) stA_SP0(T0 + 2);
    __builtin_amdgcn_s_barrier();
    mma(0, 1);
    __builtin_amdgcn_s_barrier();
    // ph3
    rdA(sA0, 1);
    if (pre) stB_H0(T0 + 2);
    __builtin_amdgcn_s_barrier();
    mma(1, 0);
    __builtin_amdgcn_s_barrier();
    // ph4
    if (pre) stA_SP1(T0 + 2);
    __builtin_amdgcn_s_barrier();
    mma(1, 1);
    if (pre) { asm volatile("s_waitcnt vmcnt(6)" ::: "memory"); }
    else     { asm volatile("s_waitcnt vmcnt(0)" ::: "memory"); }
    __builtin_amdgcn_s_barrier();                  // T1 fully resident

    // ph5
    rdB(sB1, 0); rdA(sA1, 0);
    if (pre) stB_H1(T0 + 2);
    __builtin_amdgcn_s_barrier();
    mma(0, 0);
    __builtin_amdgcn_s_barrier();
    // ph6
    rdB(sB1, 1);
    if (pre) stA_SP0(T1 + 2);
    __builtin_amdgcn_s_barrier();
    mma(0, 1);
    __builtin_amdgcn_s_barrier();
    // ph7
    rdA(sA1, 1);
    if (pre) stB_H0(T1 + 2);
    __builtin_amdgcn_s_barrier();
    mma(1, 0);
    __builtin_amdgcn_s_barrier();
    // ph8
    if (pre) stA_SP1(T1 + 2);
    __builtin_amdgcn_s_barrier();
    mma(1, 1);
    if (pre) { asm volatile("s_waitcnt vmcnt(6)" ::: "memory"); }
    __builtin_amdgcn_s_barrier();                  // T0+2 fully resident
  }

  // epilogue: row = bm*256 + wm*128 + m*16 + l4*4 + r ; col = col0 + bn*256 + wn*64 + n*16 + l15
  const int row_base = bm * 256 + wm * 128;
#pragma unroll
  for (int m = 0; m < 8; ++m) {
#pragma unroll
    for (int n = 0; n < 4; ++n) {
      int colg = bn * 256 + wn * 64 + n * 16 + l15;
#pragma unroll
      for (int r = 0; r < 4; ++r) {
        int row = row_base + m * 16 + l4 * 4 + r;
        float val = acc[m][n][r];
        if (EPI == 4) {
          outf[(size_t)row * Nst + col0 + colg] = val;
        } else if (EPI == 2) {
          int col = col0 + colg;
          float v2 = val + bias[col];
          v2 = 0.5f * v2 * (1.0f + erff(v2 * 0.7071067811865475f));
          outb[(size_t)row * Nst + col] = (bf16_t)v2;
        } else {   // EPI 5: QKV split into three contiguous [M,1024] buffers
          int buf = colg >> 10;
          int lc  = colg & 1023;
          (outb + (size_t)buf * 4194304)[(size_t)row * 1024 + lc] = (bf16_t)val;
        }
      }
    }
  }
}

// ---------------- flash attention (causal), 1 block = (b, h, 64 q-rows) ----------------
// V stored column-rotated: Vs[d][ (j + (d&56)) & 63 ] = V[j][d]  -> conflict-free
__global__ __launch_bounds__(256) void attn_kernel(
    const bf16_t* __restrict__ q, const bf16_t* __restrict__ k,
    const bf16_t* __restrict__ v, bf16_t* __restrict__ y) {
  int bid = blockIdx.x;
  int qt = bid & 15;
  int h  = (bid >> 4) & (H_ - 1);
  int b  = bid >> 8;
  int tid = threadIdx.x, wid = tid >> 6, lane = tid & 63;
  int l15 = lane & 15, l4 = lane >> 4;

  __shared__ __align__(16) bf16_t Ks[64 * 72];
  __shared__ __align__(16) bf16_t Vs[64 * 72];
  __shared__ __align__(16) bf16_t Ps[4][16 * 72];

  const int qrow0 = qt * 64 + wid * 16;
  const size_t bh = ((size_t)b * L_ * H_ + h) * HD_;

  bf16x8 qf[2];
#pragma unroll
  for (int c = 0; c < 2; ++c)
    qf[c] = *(const bf16x8*)(q + bh + (size_t)(qrow0 + l15) * (H_ * HD_) + c * 32 + l4 * 8);

  float m_r[4] = {-INFINITY, -INFINITY, -INFINITY, -INFINITY};
  float l_r[4] = {0.f, 0.f, 0.f, 0.f};
  f32x4 oacc[4] = {};

  for (int kt = 0; kt <= qt; ++kt) {
    __syncthreads();
    int kbase = kt * 64;
#pragma unroll
    for (int s = 0; s < 2; ++s) {
      int seg = s * 256 + tid;
      int j = seg >> 3;
      int dof = (seg & 7) * 8;
      const size_t src = bh + (size_t)(kbase + j) * (H_ * HD_) + dof;
      *(bf16x8*)(Ks + j * 72 + dof) = *(const bf16x8*)(k + src);
      bf16x8 vv = *(const bf16x8*)(v + src);
      int colb = (j + dof) & 63;
#pragma unroll
      for (int jj = 0; jj < 8; ++jj) Vs[(dof + jj) * 72 + colb] = vv[jj];
    }
    __syncthreads();

    f32x4 sacc[4] = {};
#pragma unroll
    for (int c = 0; c < 2; ++c) {
#pragma unroll
      for (int t = 0; t < 4; ++t) {
        bf16x8 kf = *(const bf16x8*)(Ks + (t * 16 + l15) * 72 + c * 32 + l4 * 8);
        sacc[t] = __builtin_amdgcn_mfma_f32_16x16x32_bf16(qf[c], kf, sacc[t], 0, 0, 0);
      }
    }

    float tmax[4] = {-INFINITY, -INFINITY, -INFINITY, -INFINITY};
#pragma unroll
    for (int t = 0; t < 4; ++t) {
#pragma unroll
      for (int r = 0; r < 4; ++r) {
        float sv = sacc[t][r] * 0.125f;
        int kj = kbase + t * 16 + l15;
        int qi = qrow0 + l4 * 4 + r;
        if (kj > qi) sv = -INFINITY;
        sacc[t][r] = sv;
        tmax[r] = fmaxf(tmax[r], sv);
      }
    }
#pragma unroll
    for (int r = 0; r < 4; ++r) {
#pragma unroll
      for (int md = 1; md < 16; md <<= 1)
        tmax[r] = fmaxf(tmax[r], __shfl_xor(tmax[r], md));
    }
    float alpha[4], tsum[4];
#pragma unroll
    for (int r = 0; r < 4; ++r) {
      float mn = fmaxf(m_r[r], tmax[r]);
      alpha[r] = expf(m_r[r] - mn);
      m_r[r] = mn;
      tsum[r] = 0.f;
    }
#pragma unroll
    for (int t = 0; t < 4; ++t) {
#pragma unroll
      for (int r = 0; r < 4; ++r) {
        float p = expf(sacc[t][r] - m_r[r]);
        tsum[r] += p;
        Ps[wid][(l4 * 4 + r) * 72 + t * 16 + l15] = (bf16_t)p;
      }
    }
#pragma unroll
    for (int r = 0; r < 4; ++r) {
#pragma unroll
      for (int md = 1; md < 16; md <<= 1)
        tsum[r] += __shfl_xor(tsum[r], md);
      l_r[r] = l_r[r] * alpha[r] + tsum[r];
    }
#pragma unroll
    for (int t = 0; t < 4; ++t)
#pragma unroll
      for (int r = 0; r < 4; ++r)
        oacc[t][r] *= alpha[r];

#pragma unroll
    for (int c = 0; c < 2; ++c) {
      bf16x8 pf = *(const bf16x8*)(&Ps[wid][l15 * 72 + c * 32 + l4 * 8]);
#pragma unroll
      for (int t = 0; t < 4; ++t) {
        int d = t * 16 + l15;
        int jb = c * 32 + l4 * 8;
        bf16x8 vf = *(const bf16x8*)(Vs + d * 72 + ((jb + (d & 56)) & 63));
        oacc[t] = __builtin_amdgcn_mfma_f32_16x16x32_bf16(pf, vf, oacc[t], 0, 0, 0);
      }
    }
  }

#pragma unroll
  for (int t = 0; t < 4; ++t) {
#pragma unroll
    for (int r = 0; r < 4; ++r) {
      int row = qrow0 + l4 * 4 + r;
      int d = t * 16 + l15;
      y[bh + (size_t)row * (H_ * HD_) + d] = (bf16_t)(oacc[t][r] / l_r[r]);
    }
  }
}

// ---------------- host launcher ----------------
extern "C" void kernel_launch(void* const* d_in, const int* in_sizes, int n_in,
                              void* d_out, int out_size, void* d_ws, size_t ws_size,
                              hipStream_t stream) {
  (void)in_sizes; (void)n_in; (void)out_size;
  const int*   idx   = (const int*)d_in[0];
  const float* emb   = (const float*)d_in[1];
  const float* ln1_s = (const float*)d_in[2];
  const float* ln1_b = (const float*)d_in[3];
  const float* wq    = (const float*)d_in[4];
  const float* wk    = (const float*)d_in[5];
  const float* wv    = (const float*)d_in[6];
  const float* wo    = (const float*)d_in[7];
  const float* ln2_s = (const float*)d_in[8];
  const float* ln2_b = (const float*)d_in[9];
  const float* w1    = (const float*)d_in[10];
  const float* b1    = (const float*)d_in[11];
  const float* w2    = (const float*)d_in[12];
  const float* b2    = (const float*)d_in[13];
  const float* lnf_s = (const float*)d_in[14];
  const float* lnf_b = (const float*)d_in[15];
  const float* headw = (const float*)d_in[16];
  float* out = (float*)d_out;

  char* ws = (char*)d_ws;
  const size_t XO  = 0;
  const size_t HBO = XO  + 16777216;     // f32 residual 4096x1024
  const size_t QBO = HBO + 8388608;      // bf16 4096x1024 each; Q,K,V contiguous
  const size_t KBO = QBO + 8388608;
  const size_t VBO = KBO + 8388608;
  const size_t YBO = VBO + 8388608;
  const size_t GBO = QBO;                // FFN intermediate overlaps Q/K/V/Y
  const size_t WTO = YBO + 8388608;      // transposed-weight staging

  float*  X  = (float*)(ws + XO);
  bf16_t* Hb = (bf16_t*)(ws + HBO);
  bf16_t* Qb = (bf16_t*)(ws + QBO);
  bf16_t* Kb = (bf16_t*)(ws + KBO);
  bf16_t* Vb = (bf16_t*)(ws + VBO);
  bf16_t* Yb = (bf16_t*)(ws + YBO);
  bf16_t* Gb = (bf16_t*)(ws + GBO);
  bf16_t* WT = (bf16_t*)(ws + WTO);

  const int M = B_ * L_;                 // 4096
  const dim3 tb(32, 8);

  embed_kernel<<<M, 256, 0, stream>>>(idx, emb, X);

  for (int l = 0; l < NL_; ++l) {
    const size_t wof = (size_t)l * D_ * D_;
    ln_kernel<<<M, 256, 0, stream>>>(X, ln1_s + (size_t)l * D_, ln1_b + (size_t)l * D_, Hb);

    // fused QKV: WT rows [0,1024)=wq^T, [1024,2048)=wk^T, [2048,3072)=wv^T
    transpose_qkv<<<dim3(D_/32, D_/32, 3), tb, 0, stream>>>(wq, wk, wv, wof, WT);
    gemm256_kernel<5><<<dim3(3*D_/256, M/256), 512, 0, stream>>>(Hb, WT, Qb, nullptr, nullptr, M, D_, D_, 0);

    attn_kernel<<<B_ * H_ * (L_/64), 256, 0, stream>>>(Qb, Kb, Vb, Yb);

    transpose_k<<<dim3(D_/32, D_/32), tb, 0, stream>>>(wo, wof, WT, D_, D_, D_);
    gemm_bt_kernel<1><<<dim3(D_/128, M/128), 256, 0, stream>>>(Yb, WT, nullptr, X, nullptr, M, D_, D_, 0);

    ln_kernel<<<M, 256, 0, stream>>>(X, ln2_s + (size_t)l * D_, ln2_b + (size_t)l * D_, Hb);

    transpose_k<<<dim3(FF_/32, D_/32), tb, 0, stream>>>(w1, (size_t)l * D_ * FF_, WT, D_, FF_, FF_);
    gemm256_kernel<2><<<dim3(FF_/256, M/256), 512, 0, stream>>>(Hb, WT, Gb, nullptr, b1 + (size_t)l * FF_, M, FF_, D_, 0);

    transpose_k<<<dim3(D_/32, FF_/32), tb, 0, stream>>>(w2, (size_t)l * FF_ * D_, WT, FF_, D_, D_);
    gemm_bt_kernel<3><<<dim3(D_/128, M/128), 256, 0, stream>>>(Gb, WT, nullptr, X, b2 + (size_t)l * D_, M, D_, FF_, 0);
  }

  ln_kernel<<<M, 256, 0, stream>>>(X, lnf_s, lnf_b, Hb);

  // head GEMM -> f32 logits, N-chunked (256-multiples) to fit ws
  size_t avail = (ws_size > WTO) ? (ws_size - WTO) : 0;
  long long maxcols = (long long)(avail / ((size_t)D_ * 2));
  int chunk = (int)((maxcols / 256) * 256);
  if (chunk > V_) chunk = V_;
  if (chunk < 256) chunk = 256;
  for (int n0 = 0; n0 < V_; n0 += chunk) {
    int nc = (V_ - n0 < chunk) ? (V_ - n0) : chunk;
    transpose_k<<<dim3(nc/32, D_/32), tb, 0, stream>>>(headw, (size_t)n0, WT, D_, nc, V_);
    gemm256_kernel<4><<<dim3(nc/256, M/256), 512, 0, stream>>>(Hb, WT, nullptr, out, nullptr, M, V_, D_, n0);
  }
}

// Round 12
// 2934.147 us; speedup vs baseline: 1.0648x; 1.0352x over previous
//
#include <hip/hip_runtime.h>
#include <hip/hip_bf16.h>
#include <math.h>

typedef __bf16 bf16_t;
typedef __attribute__((ext_vector_type(8))) __bf16 bf16x8;
typedef __attribute__((ext_vector_type(4))) float f32x4;

#define B_  4
#define L_  1024
#define D_  1024
#define H_  16
#define HD_ 64
#define NL_ 8
#define V_  32000
#define FF_ 4096

// ---------------- embed + sinusoidal PE -> f32 residual ----------------
__global__ __launch_bounds__(256) void embed_kernel(const int* __restrict__ idx,
                                                    const float* __restrict__ emb,
                                                    float* __restrict__ x) {
  int token = blockIdx.x;           // b*L + l
  int l = token & (L_ - 1);
  int id = idx[token];
  const float* erow = emb + (size_t)id * D_;
  float* xrow = x + (size_t)token * D_;
  int d0 = threadIdx.x * 4;
#pragma unroll
  for (int j = 0; j < 4; ++j) {
    int d = d0 + j;
    int i = d >> 1;
    float freq = expf((float)(2 * i) * (-9.210340371976184f / (float)D_));
    float ang = (float)l * freq;
    float pe = (d & 1) ? cosf(ang) : sinf(ang);
    xrow[d] = erow[d] + pe;
  }
}

// ---------------- LayerNorm: f32 in -> bf16 out ----------------
__global__ __launch_bounds__(256) void ln_kernel(const float* __restrict__ x,
                                                 const float* __restrict__ gamma,
                                                 const float* __restrict__ beta,
                                                 bf16_t* __restrict__ out) {
  int row = blockIdx.x;
  int t = threadIdx.x;
  float4 v = ((const float4*)(x + (size_t)row * D_))[t];
  float va[4] = {v.x, v.y, v.z, v.w};
  float s = va[0] + va[1] + va[2] + va[3];
  float ss = va[0]*va[0] + va[1]*va[1] + va[2]*va[2] + va[3]*va[3];
#pragma unroll
  for (int m = 1; m < 64; m <<= 1) {
    s  += __shfl_xor(s, m);
    ss += __shfl_xor(ss, m);
  }
  __shared__ float red[8];
  int wid = t >> 6, lane = t & 63;
  if (lane == 0) { red[wid] = s; red[4 + wid] = ss; }
  __syncthreads();
  s  = red[0] + red[1] + red[2] + red[3];
  ss = red[4] + red[5] + red[6] + red[7];
  float mu  = s * (1.0f / D_);
  float var = fmaxf(ss * (1.0f / D_) - mu * mu, 0.0f);
  float rstd = rsqrtf(var + 1e-5f);
  int d0 = t * 4;
  bf16_t* orow = out + (size_t)row * D_ + d0;
#pragma unroll
  for (int j = 0; j < 4; ++j) {
    int d = d0 + j;
    orow[j] = (bf16_t)((va[j] - mu) * rstd * gamma[d] + beta[d]);
  }
}

// ------- transpose + f32->bf16 (single job; used for head chunks) -------
__global__ void transpose_k(const float* __restrict__ in, size_t base,
                            bf16_t* __restrict__ out, int K, int N, int ldin) {
  __shared__ bf16_t tile[32][33];
  int n0 = blockIdx.x * 32, k0 = blockIdx.y * 32;
#pragma unroll
  for (int r = 0; r < 4; ++r) {
    int kk = threadIdx.y + r * 8;
    tile[kk][threadIdx.x] = (bf16_t)in[base + (size_t)(k0 + kk) * ldin + n0 + threadIdx.x];
  }
  __syncthreads();
#pragma unroll
  for (int r = 0; r < 4; ++r) {
    int nn = threadIdx.y + r * 8;
    out[(size_t)(n0 + nn) * K + k0 + threadIdx.x] = tile[threadIdx.x][nn];
  }
}

// ------- fused per-layer transpose: qkv(3x 1024^2) + wo(1024^2) + w1(1024x4096) + w2(4096x1024) -------
// flat grid of 12288 32x32 tiles, job-decoded.
__global__ void transpose_layer(const float* __restrict__ wq, const float* __restrict__ wk,
                                const float* __restrict__ wv, const float* __restrict__ wo,
                                const float* __restrict__ w1, const float* __restrict__ w2,
                                size_t wofD, size_t wofF,
                                bf16_t* __restrict__ qkvT, bf16_t* __restrict__ woT,
                                bf16_t* __restrict__ w1T, bf16_t* __restrict__ w2T) {
  int t = blockIdx.x;
  const float* in; bf16_t* out; int K, N, ldin, x, y;
  if (t < 3072) {           // qkv
    int z = t >> 10, tt = t & 1023;
    in = (z == 0 ? wq : z == 1 ? wk : wv) + wofD;
    out = qkvT + (size_t)z * D_ * D_;
    K = D_; N = D_; ldin = D_; x = tt & 31; y = tt >> 5;
  } else if (t < 4096) {    // wo
    int tt = t - 3072;
    in = wo + wofD; out = woT;
    K = D_; N = D_; ldin = D_; x = tt & 31; y = tt >> 5;
  } else if (t < 8192) {    // w1: [D][FF] -> [FF][D]
    int tt = t - 4096;
    in = w1 + wofF; out = w1T;
    K = D_; N = FF_; ldin = FF_; x = tt & 127; y = tt >> 7;
  } else {                  // w2: [FF][D] -> [D][FF]
    int tt = t - 8192;
    in = w2 + wofF; out = w2T;
    K = FF_; N = D_; ldin = D_; x = tt & 31; y = tt >> 5;
  }
  __shared__ bf16_t tile[32][33];
  int n0 = x * 32, k0 = y * 32;
#pragma unroll
  for (int r = 0; r < 4; ++r) {
    int kk = threadIdx.y + r * 8;
    tile[kk][threadIdx.x] = (bf16_t)in[(size_t)(k0 + kk) * ldin + n0 + threadIdx.x];
  }
  __syncthreads();
#pragma unroll
  for (int r = 0; r < 4; ++r) {
    int nn = threadIdx.y + r * 8;
    out[(size_t)(n0 + nn) * K + k0 + threadIdx.x] = tile[threadIdx.x][nn];
  }
}

// ---------------- async global->LDS helper ----------------
__device__ __forceinline__ void gload_lds16(const bf16_t* g, bf16_t* lds) {
  __builtin_amdgcn_global_load_lds(
      (const __attribute__((address_space(1))) void*)g,
      (__attribute__((address_space(3))) void*)(void*)lds,
      16, 0, 0);
}

// ---- common bijective XCD + grouped-raster block remap (G=8 bm rows/group) ----
__device__ __forceinline__ void remap_block(int& bn, int& bm) {
  const int gx = gridDim.x, gy = gridDim.y;
  int lin = blockIdx.y * gx + blockIdx.x;
  int nwg = gx * gy;
  int q8 = nwg >> 3, r8 = nwg & 7;
  int xcd = lin & 7, pos = lin >> 3;
  int wg = (xcd < r8 ? xcd * (q8 + 1) : r8 * (q8 + 1) + (xcd - r8) * q8) + pos;
  if ((gy & 7) == 0) {
    int per = gx << 3;
    int grp = wg / per, win = wg % per;
    bm = (grp << 3) + (win & 7);
    bn = win >> 3;
  } else { bn = wg % gx; bm = wg / gx; }
}

// ---------------- 128x128 GEMM (m97 structure) with split-K over blockIdx.z ----------------
// EPI: 1 = atomicAdd resid; 3 = atomicAdd resid (+bias on split 0)
template <int EPI>
__global__ __launch_bounds__(256) void gemm_bt_kernel(
    const bf16_t* __restrict__ A, const bf16_t* __restrict__ Bt,
    bf16_t* __restrict__ outb, float* __restrict__ outf,
    const float* __restrict__ bias, int M, int Nst, int K, int col0) {
  int bn, bm; remap_block(bn, bm);
  const int kz = blockIdx.z, KS = gridDim.z;
  const int Kc = K / KS;
  const int kbeg = kz * Kc, kend = kbeg + Kc;
  const int tid = threadIdx.x, wid = tid >> 6, lane = tid & 63;
  const int wm = wid >> 1, wn = wid & 1;
  const int l15 = lane & 15, l4 = lane >> 4;

  __shared__ __align__(16) bf16_t As[128 * 32];
  __shared__ __align__(16) bf16_t Bs[128 * 32];

  f32x4 acc[4][4] = {};

  const bf16_t* Ablk = A  + (size_t)(bm * 128) * K;
  const bf16_t* Bblk = Bt + (size_t)(bn * 128) * K;
  const int srow = lane >> 2;
  const int skof = (lane & 3) * 8;

  for (int k0 = kbeg; k0 < kend; k0 += 32) {
#pragma unroll
    for (int c = 0; c < 2; ++c) {
      int chunk = wid * 2 + c;
      int row = chunk * 16 + srow;
      gload_lds16(Ablk + (size_t)row * K + k0 + skof, As + chunk * 512);
      gload_lds16(Bblk + (size_t)row * K + k0 + skof, Bs + chunk * 512);
    }
    __syncthreads();

    bf16x8 af[4], bfv[4];
#pragma unroll
    for (int i = 0; i < 4; ++i)
      af[i] = *(const bf16x8*)(As + (wm * 64 + i * 16 + l15) * 32 + l4 * 8);
#pragma unroll
    for (int j = 0; j < 4; ++j)
      bfv[j] = *(const bf16x8*)(Bs + (wn * 64 + j * 16 + l15) * 32 + l4 * 8);
#pragma unroll
    for (int i = 0; i < 4; ++i)
#pragma unroll
      for (int j = 0; j < 4; ++j)
        acc[i][j] = __builtin_amdgcn_mfma_f32_16x16x32_bf16(af[i], bfv[j], acc[i][j], 0, 0, 0);
    __syncthreads();
  }

  const int row_base = bm * 128 + wm * 64;
  const int col_base = col0 + bn * 128 + wn * 64 + l15;
#pragma unroll
  for (int i = 0; i < 4; ++i) {
#pragma unroll
    for (int j = 0; j < 4; ++j) {
      int col = col_base + j * 16;
#pragma unroll
      for (int r = 0; r < 4; ++r) {
        int row = row_base + i * 16 + l4 * 4 + r;
        float val = acc[i][j][r];
        if (EPI == 3 && kz == 0) val += bias[col];
        atomicAdd(&outf[(size_t)row * Nst + col], val);
      }
    }
  }
}

// ------- 256x256 8-wave GEMM, BK=64, 8-phase schedule, race-free stage map -------
// (verified round 11) EPI: 2 = +bias,gelu,bf16; 4 = f32; 5 = QKV split
template <int EPI>
__global__ __launch_bounds__(512, 2) void gemm256_kernel(
    const bf16_t* __restrict__ A, const bf16_t* __restrict__ Bt,
    bf16_t* __restrict__ outb, float* __restrict__ outf,
    const float* __restrict__ bias, int M, int Nst, int K, int col0) {
  int bn, bm; remap_block(bn, bm);
  const int tid = threadIdx.x, wid = tid >> 6, lane = tid & 63;
  const int wm = wid >> 2, wn = wid & 3;          // 2 x 4 waves
  const int l15 = lane & 15, l4 = lane >> 4;

  __shared__ __align__(16) bf16_t smem[65536];

  f32x4 acc[8][4] = {};

  const bf16_t* Ab = A  + (size_t)(bm * 256) * K;
  const bf16_t* Bb = Bt + (size_t)(bn * 256) * K;
  const int NT = K >> 6;

  const int srow = tid >> 3;
  const int sx8  = tid & 7;
  const int xrd  = l15 & 7;

  auto stage_rows = [&](int t, int mat, int R) {
    const bf16_t* g = mat ? Bb : Ab;
    bf16_t* l = smem + (t & 1) * 32768 + mat * 16384 + R * 64;
    int row = R + srow;
    int gs  = sx8 ^ (row & 7);
    gload_lds16(g + (size_t)row * K + t * 64 + gs * 8, l + wid * 512);
  };
  auto stA_SP0 = [&](int t) { stage_rows(t, 0, 0);   stage_rows(t, 0, 128); };
  auto stA_SP1 = [&](int t) { stage_rows(t, 0, 64);  stage_rows(t, 0, 192); };
  auto stB_H0  = [&](int t) { stage_rows(t, 1, 0);   stage_rows(t, 1, 64);  };
  auto stB_H1  = [&](int t) { stage_rows(t, 1, 128); stage_rows(t, 1, 192); };

  stA_SP0(0); stB_H0(0); stA_SP1(0); stB_H1(0);
  stA_SP0(1); stB_H0(1); stA_SP1(1);
  asm volatile("s_waitcnt vmcnt(6)" ::: "memory");
  __builtin_amdgcn_s_barrier();

  bf16x8 af[4][2], bfr[4][2];

  auto rdB = [&](const bf16_t* sB, int nh) {
#pragma unroll
    for (int n = 0; n < 2; ++n)
#pragma unroll
      for (int ks = 0; ks < 2; ++ks)
        bfr[nh * 2 + n][ks] = *(const bf16x8*)(sB + (wn * 64 + (nh * 2 + n) * 16 + l15) * 64
                                                  + ((ks * 4 + l4) ^ xrd) * 8);
  };
  auto rdA = [&](const bf16_t* sA, int mh) {
#pragma unroll
    for (int m = 0; m < 4; ++m)
#pragma unroll
      for (int ks = 0; ks < 2; ++ks)
        af[m][ks] = *(const bf16x8*)(sA + (wm * 128 + mh * 64 + m * 16 + l15) * 64
                                        + ((ks * 4 + l4) ^ xrd) * 8);
  };
  auto mma = [&](int mh, int nh) {
    asm volatile("s_waitcnt lgkmcnt(0)" ::: "memory");
    __builtin_amdgcn_sched_barrier(0);
    __builtin_amdgcn_s_setprio(1);
#pragma unroll
    for (int m = 0; m < 4; ++m)
#pragma unroll
      for (int n = 0; n < 2; ++n)
#pragma unroll
        for (int ks = 0; ks < 2; ++ks)
          acc[mh * 4 + m][nh * 2 + n] = __builtin_amdgcn_mfma_f32_16x16x32_bf16(
              af[m][ks], bfr[nh * 2 + n][ks], acc[mh * 4 + m][nh * 2 + n], 0, 0, 0);
    __builtin_amdgcn_s_setprio(0);
  };

  const int NI = NT >> 1;
  for (int it = 0; it < NI; ++it) {
    const int T0 = 2 * it, T1 = 2 * it + 1;
    const bool pre = (it + 1 < NI);
    const bf16_t* sA0 = smem;
    const bf16_t* sB0 = smem + 16384;
    const bf16_t* sA1 = smem + 32768;
    const bf16_t* sB1 = smem + 49152;

    rdB(sB0, 0); rdA(sA0, 0);
    stB_H1(T1);
    __builtin_amdgcn_s_barrier();
    mma(0, 0);
    __builtin_amdgcn_s_barrier();
    rdB(sB0, 1);
    if (pre) stA_SP0(T0 + 2);
    __builtin_amdgcn_s_barrier();
    mma(0, 1);
    __builtin_amdgcn_s_barrier();
    rdA(sA0, 1);
    if (pre) stB_H0(T0 + 2);
    __builtin_amdgcn_s_barrier();
    mma(1, 0);
    __builtin_amdgcn_s_barrier();
    if (pre) stA_SP1(T0 + 2);
    __builtin_amdgcn_s_barrier();
    mma(1, 1);
    if (pre) { asm volatile("s_waitcnt vmcnt(6)" ::: "memory"); }
    else     { asm volatile("s_waitcnt vmcnt(0)" ::: "memory"); }
    __builtin_amdgcn_s_barrier();

    rdB(sB1, 0); rdA(sA1, 0);
    if (pre) stB_H1(T0 + 2);
    __builtin_amdgcn_s_barrier();
    mma(0, 0);
    __builtin_amdgcn_s_barrier();
    rdB(sB1, 1);
    if (pre) stA_SP0(T1 + 2);
    __builtin_amdgcn_s_barrier();
    mma(0, 1);
    __builtin_amdgcn_s_barrier();
    rdA(sA1, 1);
    if (pre) stB_H0(T1 + 2);
    __builtin_amdgcn_s_barrier();
    mma(1, 0);
    __builtin_amdgcn_s_barrier();
    if (pre) stA_SP1(T1 + 2);
    __builtin_amdgcn_s_barrier();
    mma(1, 1);
    if (pre) { asm volatile("s_waitcnt vmcnt(6)" ::: "memory"); }
    __builtin_amdgcn_s_barrier();
  }

  const int row_base = bm * 256 + wm * 128;
#pragma unroll
  for (int m = 0; m < 8; ++m) {
#pragma unroll
    for (int n = 0; n < 4; ++n) {
      int colg = bn * 256 + wn * 64 + n * 16 + l15;
#pragma unroll
      for (int r = 0; r < 4; ++r) {
        int row = row_base + m * 16 + l4 * 4 + r;
        float val = acc[m][n][r];
        if (EPI == 4) {
          outf[(size_t)row * Nst + col0 + colg] = val;
        } else if (EPI == 2) {
          int col = col0 + colg;
          float v2 = val + bias[col];
          v2 = 0.5f * v2 * (1.0f + erff(v2 * 0.7071067811865475f));
          outb[(size_t)row * Nst + col] = (bf16_t)v2;
        } else {
          int buf = colg >> 10;
          int lc  = colg & 1023;
          (outb + (size_t)buf * 4194304)[(size_t)row * 1024 + lc] = (bf16_t)val;
        }
      }
    }
  }
}

// ---------------- flash attention (causal), 1 block = (b, h, 64 q-rows) ----------------
__global__ __launch_bounds__(256) void attn_kernel(
    const bf16_t* __restrict__ q, const bf16_t* __restrict__ k,
    const bf16_t* __restrict__ v, bf16_t* __restrict__ y) {
  int bid = blockIdx.x;
  int qt = bid & 15;
  int h  = (bid >> 4) & (H_ - 1);
  int b  = bid >> 8;
  int tid = threadIdx.x, wid = tid >> 6, lane = tid & 63;
  int l15 = lane & 15, l4 = lane >> 4;

  __shared__ __align__(16) bf16_t Ks[64 * 72];
  __shared__ __align__(16) bf16_t Vs[64 * 72];
  __shared__ __align__(16) bf16_t Ps[4][16 * 72];

  const int qrow0 = qt * 64 + wid * 16;
  const size_t bh = ((size_t)b * L_ * H_ + h) * HD_;

  bf16x8 qf[2];
#pragma unroll
  for (int c = 0; c < 2; ++c)
    qf[c] = *(const bf16x8*)(q + bh + (size_t)(qrow0 + l15) * (H_ * HD_) + c * 32 + l4 * 8);

  float m_r[4] = {-INFINITY, -INFINITY, -INFINITY, -INFINITY};
  float l_r[4] = {0.f, 0.f, 0.f, 0.f};
  f32x4 oacc[4] = {};

  for (int kt = 0; kt <= qt; ++kt) {
    __syncthreads();
    int kbase = kt * 64;
#pragma unroll
    for (int s = 0; s < 2; ++s) {
      int seg = s * 256 + tid;
      int j = seg >> 3;
      int dof = (seg & 7) * 8;
      const size_t src = bh + (size_t)(kbase + j) * (H_ * HD_) + dof;
      *(bf16x8*)(Ks + j * 72 + dof) = *(const bf16x8*)(k + src);
      bf16x8 vv = *(const bf16x8*)(v + src);
      int colb = (j + dof) & 63;
#pragma unroll
      for (int jj = 0; jj < 8; ++jj) Vs[(dof + jj) * 72 + colb] = vv[jj];
    }
    __syncthreads();

    f32x4 sacc[4] = {};
#pragma unroll
    for (int c = 0; c < 2; ++c) {
#pragma unroll
      for (int t = 0; t < 4; ++t) {
        bf16x8 kf = *(const bf16x8*)(Ks + (t * 16 + l15) * 72 + c * 32 + l4 * 8);
        sacc[t] = __builtin_amdgcn_mfma_f32_16x16x32_bf16(qf[c], kf, sacc[t], 0, 0, 0);
      }
    }

    float tmax[4] = {-INFINITY, -INFINITY, -INFINITY, -INFINITY};
#pragma unroll
    for (int t = 0; t < 4; ++t) {
#pragma unroll
      for (int r = 0; r < 4; ++r) {
        float sv = sacc[t][r] * 0.125f;
        int kj = kbase + t * 16 + l15;
        int qi = qrow0 + l4 * 4 + r;
        if (kj > qi) sv = -INFINITY;
        sacc[t][r] = sv;
        tmax[r] = fmaxf(tmax[r], sv);
      }
    }
#pragma unroll
    for (int r = 0; r < 4; ++r) {
#pragma unroll
      for (int md = 1; md < 16; md <<= 1)
        tmax[r] = fmaxf(tmax[r], __shfl_xor(tmax[r], md));
    }
    float alpha[4], tsum[4];
#pragma unroll
    for (int r = 0; r < 4; ++r) {
      float mn = fmaxf(m_r[r], tmax[r]);
      alpha[r] = expf(m_r[r] - mn);
      m_r[r] = mn;
      tsum[r] = 0.f;
    }
#pragma unroll
    for (int t = 0; t < 4; ++t) {
#pragma unroll
      for (int r = 0; r < 4; ++r) {
        float p = expf(sacc[t][r] - m_r[r]);
        tsum[r] += p;
        Ps[wid][(l4 * 4 + r) * 72 + t * 16 + l15] = (bf16_t)p;
      }
    }
#pragma unroll
    for (int r = 0; r < 4; ++r) {
#pragma unroll
      for (int md = 1; md < 16; md <<= 1)
        tsum[r] += __shfl_xor(tsum[r], md);
      l_r[r] = l_r[r] * alpha[r] + tsum[r];
    }
#pragma unroll
    for (int t = 0; t < 4; ++t)
#pragma unroll
      for (int r = 0; r < 4; ++r)
        oacc[t][r] *= alpha[r];

#pragma unroll
    for (int c = 0; c < 2; ++c) {
      bf16x8 pf = *(const bf16x8*)(&Ps[wid][l15 * 72 + c * 32 + l4 * 8]);
#pragma unroll
      for (int t = 0; t < 4; ++t) {
        int d = t * 16 + l15;
        int jb = c * 32 + l4 * 8;
        bf16x8 vf = *(const bf16x8*)(Vs + d * 72 + ((jb + (d & 56)) & 63));
        oacc[t] = __builtin_amdgcn_mfma_f32_16x16x32_bf16(pf, vf, oacc[t], 0, 0, 0);
      }
    }
  }

#pragma unroll
  for (int t = 0; t < 4; ++t) {
#pragma unroll
    for (int r = 0; r < 4; ++r) {
      int row = qrow0 + l4 * 4 + r;
      int d = t * 16 + l15;
      y[bh + (size_t)row * (H_ * HD_) + d] = (bf16_t)(oacc[t][r] / l_r[r]);
    }
  }
}

// ---------------- host launcher ----------------
extern "C" void kernel_launch(void* const* d_in, const int* in_sizes, int n_in,
                              void* d_out, int out_size, void* d_ws, size_t ws_size,
                              hipStream_t stream) {
  (void)in_sizes; (void)n_in; (void)out_size;
  const int*   idx   = (const int*)d_in[0];
  const float* emb   = (const float*)d_in[1];
  const float* ln1_s = (const float*)d_in[2];
  const float* ln1_b = (const float*)d_in[3];
  const float* wq    = (const float*)d_in[4];
  const float* wk    = (const float*)d_in[5];
  const float* wv    = (const float*)d_in[6];
  const float* wo    = (const float*)d_in[7];
  const float* ln2_s = (const float*)d_in[8];
  const float* ln2_b = (const float*)d_in[9];
  const float* w1    = (const float*)d_in[10];
  const float* b1    = (const float*)d_in[11];
  const float* w2    = (const float*)d_in[12];
  const float* b2    = (const float*)d_in[13];
  const float* lnf_s = (const float*)d_in[14];
  const float* lnf_b = (const float*)d_in[15];
  const float* headw = (const float*)d_in[16];
  float* out = (float*)d_out;

  char* ws = (char*)d_ws;
  const size_t XO  = 0;
  const size_t HBO = XO  + 16777216;     // f32 residual 4096x1024
  const size_t QBO = HBO + 8388608;      // bf16 4096x1024 each; Q,K,V contiguous
  const size_t KBO = QBO + 8388608;
  const size_t VBO = KBO + 8388608;
  const size_t YBO = VBO + 8388608;
  const size_t GBO = QBO;                // FFN intermediate overlaps Q/K/V/Y
  const size_t WTO = YBO + 8388608;      // weight-transpose staging region
  // sub-buffers inside WTO (bytes): qkvT 6MB | woT 2MB | w1T 8MB | w2T 8MB
  const size_t QKVT = WTO;
  const size_t WOT  = QKVT + 6291456;
  const size_t W1T  = WOT + 2097152;
  const size_t W2T  = W1T + 8388608;
  const size_t HDT  = WTO;               // head transpose reuses region after layers

  float*  X   = (float*)(ws + XO);
  bf16_t* Hb  = (bf16_t*)(ws + HBO);
  bf16_t* Qb  = (bf16_t*)(ws + QBO);
  bf16_t* Kb  = (bf16_t*)(ws + KBO);
  bf16_t* Vb  = (bf16_t*)(ws + VBO);
  bf16_t* Yb  = (bf16_t*)(ws + YBO);
  bf16_t* Gb  = (bf16_t*)(ws + GBO);
  bf16_t* qkvT = (bf16_t*)(ws + QKVT);
  bf16_t* woT  = (bf16_t*)(ws + WOT);
  bf16_t* w1T  = (bf16_t*)(ws + W1T);
  bf16_t* w2T  = (bf16_t*)(ws + W2T);
  bf16_t* WT   = (bf16_t*)(ws + HDT);

  const int M = B_ * L_;                 // 4096
  const dim3 tb(32, 8);

  embed_kernel<<<M, 256, 0, stream>>>(idx, emb, X);

  for (int l = 0; l < NL_; ++l) {
    const size_t wofD = (size_t)l * D_ * D_;
    const size_t wofF = (size_t)l * D_ * FF_;

    ln_kernel<<<M, 256, 0, stream>>>(X, ln1_s + (size_t)l * D_, ln1_b + (size_t)l * D_, Hb);

    transpose_layer<<<12288, tb, 0, stream>>>(wq, wk, wv, wo, w1, w2, wofD, wofF,
                                              qkvT, woT, w1T, w2T);

    gemm256_kernel<5><<<dim3(3*D_/256, M/256), 512, 0, stream>>>(Hb, qkvT, Qb, nullptr, nullptr, M, D_, D_, 0);

    attn_kernel<<<B_ * H_ * (L_/64), 256, 0, stream>>>(Qb, Kb, Vb, Yb);

    gemm_bt_kernel<1><<<dim3(D_/128, M/128, 2), 256, 0, stream>>>(Yb, woT, nullptr, X, nullptr, M, D_, D_, 0);

    ln_kernel<<<M, 256, 0, stream>>>(X, ln2_s + (size_t)l * D_, ln2_b + (size_t)l * D_, Hb);

    gemm256_kernel<2><<<dim3(FF_/256, M/256), 512, 0, stream>>>(Hb, w1T, Gb, nullptr, b1 + (size_t)l * FF_, M, FF_, D_, 0);

    gemm_bt_kernel<3><<<dim3(D_/128, M/128, 4), 256, 0, stream>>>(Gb, w2T, nullptr, X, b2 + (size_t)l * D_, M, D_, FF_, 0);
  }

  ln_kernel<<<M, 256, 0, stream>>>(X, lnf_s, lnf_b, Hb);

  // head GEMM -> f32 logits, N-chunked (256-multiples) to fit ws
  size_t avail = (ws_size > HDT) ? (ws_size - HDT) : 0;
  long long maxcols = (long long)(avail / ((size_t)D_ * 2));
  int chunk = (int)((maxcols / 256) * 256);
  if (chunk > V_) chunk = V_;
  if (chunk < 256) chunk = 256;
  for (int n0 = 0; n0 < V_; n0 += chunk) {
    int nc = (V_ - n0 < chunk) ? (V_ - n0) : chunk;
    transpose_k<<<dim3(nc/32, D_/32), tb, 0, stream>>>(headw, (size_t)n0, WT, D_, nc, V_);
    gemm256_kernel<4><<<dim3(nc/256, M/256), 512, 0, stream>>>(Hb, WT, nullptr, out, nullptr, M, V_, D_, n0);
  }
}